// Round 3
// baseline (13757.443 us; speedup 1.0000x reference)
//
#include <hip/hip_runtime.h>
#include <cmath>

__device__ __forceinline__ float sigm(float x) { return 1.0f / (1.0f + __expf(-x)); }

// ---------------- tiled transpose [2048][K] -> [K][2048] ----------------
__global__ __launch_bounds__(256) void transpose_w(const float* __restrict__ in,
                                                   float* __restrict__ outT, int K) {
  __shared__ float tile[32][33];
  int tx = threadIdx.x & 31, ty = threadIdx.x >> 5;
  int k0 = blockIdx.x * 32;
  int j0 = blockIdx.y * 32;
#pragma unroll
  for (int i = 0; i < 32; i += 8)
    tile[ty + i][tx] = in[(size_t)(j0 + ty + i) * K + k0 + tx];
  __syncthreads();
#pragma unroll
  for (int i = 0; i < 32; i += 8)
    outT[(size_t)(k0 + ty + i) * 2048 + j0 + tx] = tile[tx][ty + i];
}

// ---- persistent fused LSTM chain: 256 steps in one cooperative launch ----
// Grid 256 = 4 bg x 64 ng. Block owns 16 batches x 8 hidden units (32 gate-cols).
// WT [768][2048] = [Whh^T ; Wih^T] packed; block's slice lives in LDS all steps.
// A = [h_prev(512) | x_t(256)] per batch, restaged from global each step.
// Per-step sync: 4 independent 64-block domains via agent-scope atomics.
__global__ __launch_bounds__(256, 1) void lstm_chain(
    const float* __restrict__ WT, const float* __restrict__ x,
    const float* __restrict__ bih, const float* __restrict__ bhh,
    float* __restrict__ HBUF,   // [256][64][512]
    float* __restrict__ Cst,    // [64][512]
    unsigned int* __restrict__ cnt,  // [4]
    int is_enc) {
  extern __shared__ float lds[];
  float4* W4 = (float4*)lds;            // 768 x 8 f4 (XOR-swizzled) = 96 KB
  float4* A4 = (float4*)(lds + 24576);  // 16 x 192 f4 (XOR-swizzled) = 48 KB
  float* gates = lds + 24576 + 12288;   // 16 x 40
  const int bg = blockIdx.x >> 6, ng = blockIdx.x & 63;
  const int tid = threadIdx.x;

  // ---- stage W slice once: logical W[k][gc], gc = gate*8 + n8, k in [0,768) ----
  // f4 col j -> gate j>>1, n8 base (j&1)*4 ; phys col = j ^ ((k>>2)&7)
#pragma unroll
  for (int r = 0; r < 24; ++r) {
    int idx = tid + 256 * r;
    int k = idx >> 3, j = idx & 7;
    float4 v =
        *(const float4*)(WT + (size_t)k * 2048 + (j >> 1) * 512 + ng * 8 + (j & 1) * 4);
    W4[k * 8 + (j ^ ((k >> 2) & 7))] = v;
  }
  // ---- per-thread cell state + biases (threads 0..127 own (b,n8)) ----
  float bi_i = 0.f, bi_f = 0.f, bi_g = 0.f, bi_o = 0.f, creg = 0.f;
  if (tid < 128) {
    int b = tid >> 3, n8 = tid & 7;
    int n_g = ng * 8 + n8;
    bi_i = bih[n_g] + bhh[n_g];
    bi_f = bih[512 + n_g] + bhh[512 + n_g];
    bi_g = bih[1024 + n_g] + bhh[1024 + n_g];
    bi_o = bih[1536 + n_g] + bhh[1536 + n_g];
    if (!is_enc) creg = Cst[(size_t)(bg * 16 + b) * 512 + n_g];
  }
  // ---- initial A: h0 (zeros for encoder, HBUF row 255 for decoder) + x_0 ----
#pragma unroll
  for (int r = 0; r < 8; ++r) {
    int idx = tid + 256 * r;
    int b = idx >> 7, q = idx & 127;
    float4 v;
    if (is_enc)
      v = make_float4(0.f, 0.f, 0.f, 0.f);
    else
      v = *(const float4*)(HBUF + ((size_t)(255 * 64) + bg * 16 + b) * 512 + 4 * q);
    A4[b * 192 + (q ^ ((b >> 1) & 7))] = v;
  }
#pragma unroll
  for (int r = 0; r < 4; ++r) {
    int idx = tid + 256 * r;
    int b = idx >> 6, q = idx & 63;
    float4 v = *(const float4*)(x + ((size_t)(bg * 16 + b) * 256 + 0) * 256 + 4 * q);
    A4[b * 192 + ((128 + q) ^ ((b >> 1) & 7))] = v;
  }
  __syncthreads();

  const int w = tid >> 6;           // wave = gate (0:i 1:f 2:g 3:o)
  const int lane = tid & 63;
  const int kq = lane >> 3, b8 = lane & 7;
  const int b0 = 2 * b8, b1 = b0 + 1;
  const int jlo = (2 * w) ^ kq, jhi = (2 * w + 1) ^ kq;
  const int kqx = kq ^ b8;  // A phys low-3 for this thread's batches

  for (int t = 0; t < 256; ++t) {
    float acc0[8], acc1[8];
#pragma unroll
    for (int g = 0; g < 8; ++g) { acc0[g] = 0.f; acc1[g] = 0.f; }
#pragma unroll 2
    for (int j = 0; j < 24; ++j) {
      int qa = (j << 3) + kqx;
      float4 a0 = A4[b0 * 192 + qa];
      float4 a1 = A4[b1 * 192 + qa];
      int wr = ((j << 3) + kq) << 2;  // k = 4q
      float a0v[4] = {a0.x, a0.y, a0.z, a0.w};
      float a1v[4] = {a1.x, a1.y, a1.z, a1.w};
#pragma unroll
      for (int i = 0; i < 4; ++i) {
        float4 wlo = W4[(wr + i) * 8 + jlo];
        float4 whi = W4[(wr + i) * 8 + jhi];
        acc0[0] = fmaf(a0v[i], wlo.x, acc0[0]);
        acc0[1] = fmaf(a0v[i], wlo.y, acc0[1]);
        acc0[2] = fmaf(a0v[i], wlo.z, acc0[2]);
        acc0[3] = fmaf(a0v[i], wlo.w, acc0[3]);
        acc0[4] = fmaf(a0v[i], whi.x, acc0[4]);
        acc0[5] = fmaf(a0v[i], whi.y, acc0[5]);
        acc0[6] = fmaf(a0v[i], whi.z, acc0[6]);
        acc0[7] = fmaf(a0v[i], whi.w, acc0[7]);
        acc1[0] = fmaf(a1v[i], wlo.x, acc1[0]);
        acc1[1] = fmaf(a1v[i], wlo.y, acc1[1]);
        acc1[2] = fmaf(a1v[i], wlo.z, acc1[2]);
        acc1[3] = fmaf(a1v[i], wlo.w, acc1[3]);
        acc1[4] = fmaf(a1v[i], whi.x, acc1[4]);
        acc1[5] = fmaf(a1v[i], whi.y, acc1[5]);
        acc1[6] = fmaf(a1v[i], whi.z, acc1[6]);
        acc1[7] = fmaf(a1v[i], whi.w, acc1[7]);
      }
    }
    // reduce over kq (lane-stride 8,16,32)
#pragma unroll
    for (int d = 8; d <= 32; d <<= 1) {
#pragma unroll
      for (int g = 0; g < 8; ++g) {
        acc0[g] += __shfl_xor(acc0[g], d, 64);
        acc1[g] += __shfl_xor(acc1[g], d, 64);
      }
    }
    if (kq == 0) {
#pragma unroll
      for (int g = 0; g < 8; ++g) {
        gates[b0 * 40 + w * 8 + g] = acc0[g];
        gates[b1 * 40 + w * 8 + g] = acc1[g];
      }
    }
    __syncthreads();
    // ---- cell update + h store ----
    if (tid < 128) {
      int b = tid >> 3, n8 = tid & 7;
      float pi = gates[b * 40 + n8] + bi_i;
      float pf = gates[b * 40 + 8 + n8] + bi_f;
      float pg = gates[b * 40 + 16 + n8] + bi_g;
      float po = gates[b * 40 + 24 + n8] + bi_o;
      float ig = sigm(pi), fg = sigm(pf), gg = tanhf(pg), og = sigm(po);
      float cn = fmaf(fg, creg, ig * gg);
      if (is_enc) creg = cn;  // decoder: cell pinned at cT
      float hn = og * tanhf(cn);
      HBUF[((size_t)t * 64 + bg * 16 + b) * 512 + ng * 8 + n8] = hn;
      if (is_enc && t == 255) Cst[(size_t)(bg * 16 + b) * 512 + ng * 8 + n8] = cn;
    }
    if (t < 255) {
      __syncthreads();  // drains h stores (vmcnt 0) before release
      if (tid == 0) {
        __threadfence();  // agent release: h visible at coherent point
        __hip_atomic_fetch_add(cnt + bg, 1u, __ATOMIC_RELEASE, __HIP_MEMORY_SCOPE_AGENT);
        unsigned tgt = 64u * (unsigned)(t + 1);
        while (__hip_atomic_load(cnt + bg, __ATOMIC_ACQUIRE, __HIP_MEMORY_SCOPE_AGENT) <
               tgt)
          __builtin_amdgcn_s_sleep(2);
        __threadfence();  // agent acquire: invalidate stale L1/L2
      }
      __syncthreads();
      // ---- restage A: h_t + x_{t+1} ----
#pragma unroll
      for (int r = 0; r < 8; ++r) {
        int idx = tid + 256 * r;
        int b = idx >> 7, q = idx & 127;
        float4 v = *(const float4*)(HBUF + ((size_t)t * 64 + bg * 16 + b) * 512 + 4 * q);
        A4[b * 192 + (q ^ ((b >> 1) & 7))] = v;
      }
#pragma unroll
      for (int r = 0; r < 4; ++r) {
        int idx = tid + 256 * r;
        int b = idx >> 6, q = idx & 63;
        float4 v =
            *(const float4*)(x + ((size_t)(bg * 16 + b) * 256 + (t + 1)) * 256 + 4 * q);
        A4[b * 192 + ((128 + q) ^ ((b >> 1) & 7))] = v;
      }
      __syncthreads();
    }
  }
}

// ---- GEMM: C[r,n] = sum_k A[r][k] * W[n,k] ; 128x128 tile, 8x8 micro ----
__global__ __launch_bounds__(256) void gemm_fp32(const float* __restrict__ A,
                                                 const float* __restrict__ W,
                                                 float* __restrict__ C, int N, int K) {
  __shared__ float As[16 * 132];
  __shared__ float Ws[16 * 132];
  int tid = threadIdx.x;
  int n0 = blockIdx.x * 128, m0 = blockIdx.y * 128;
  int row = tid >> 1;
  int kbase = (tid & 1) * 8;
  const float* ap = A + (size_t)(m0 + row) * K;
  const float* wp = W + (size_t)(n0 + row) * K;
  int ty = tid >> 4, tx = tid & 15;
  float acc[8][8];
#pragma unroll
  for (int i = 0; i < 8; ++i)
#pragma unroll
    for (int j = 0; j < 8; ++j) acc[i][j] = 0.f;

  for (int kt = 0; kt < K; kt += 16) {
    float4 va0 = *(const float4*)(ap + kt + kbase);
    float4 va1 = *(const float4*)(ap + kt + kbase + 4);
    float4 vw0 = *(const float4*)(wp + kt + kbase);
    float4 vw1 = *(const float4*)(wp + kt + kbase + 4);
    __syncthreads();
    As[(kbase + 0) * 132 + row] = va0.x;
    As[(kbase + 1) * 132 + row] = va0.y;
    As[(kbase + 2) * 132 + row] = va0.z;
    As[(kbase + 3) * 132 + row] = va0.w;
    As[(kbase + 4) * 132 + row] = va1.x;
    As[(kbase + 5) * 132 + row] = va1.y;
    As[(kbase + 6) * 132 + row] = va1.z;
    As[(kbase + 7) * 132 + row] = va1.w;
    Ws[(kbase + 0) * 132 + row] = vw0.x;
    Ws[(kbase + 1) * 132 + row] = vw0.y;
    Ws[(kbase + 2) * 132 + row] = vw0.z;
    Ws[(kbase + 3) * 132 + row] = vw0.w;
    Ws[(kbase + 4) * 132 + row] = vw1.x;
    Ws[(kbase + 5) * 132 + row] = vw1.y;
    Ws[(kbase + 6) * 132 + row] = vw1.z;
    Ws[(kbase + 7) * 132 + row] = vw1.w;
    __syncthreads();
#pragma unroll
    for (int kk = 0; kk < 16; ++kk) {
      float4 a0 = *(const float4*)&As[kk * 132 + ty * 8];
      float4 a1 = *(const float4*)&As[kk * 132 + ty * 8 + 4];
      float4 w0 = *(const float4*)&Ws[kk * 132 + tx * 8];
      float4 w1 = *(const float4*)&Ws[kk * 132 + tx * 8 + 4];
      float av[8] = {a0.x, a0.y, a0.z, a0.w, a1.x, a1.y, a1.z, a1.w};
      float wv[8] = {w0.x, w0.y, w0.z, w0.w, w1.x, w1.y, w1.z, w1.w};
#pragma unroll
      for (int i = 0; i < 8; ++i)
#pragma unroll
        for (int j = 0; j < 8; ++j) acc[i][j] = fmaf(av[i], wv[j], acc[i][j]);
    }
  }
#pragma unroll
  for (int i = 0; i < 8; ++i) {
    float* cp = C + (size_t)(m0 + ty * 8 + i) * N + n0 + tx * 8;
    *(float4*)cp = make_float4(acc[i][0], acc[i][1], acc[i][2], acc[i][3]);
    *(float4*)(cp + 4) = make_float4(acc[i][4], acc[i][5], acc[i][6], acc[i][7]);
  }
}

// ---- scorer: out[b,t,s] = sum_w vt[w]*tanh(e1[s,b,w] + H2[t,b,w]) ----
__global__ __launch_bounds__(128) void scorer(const float* __restrict__ E1,
                                              const float* __restrict__ H2,
                                              const float* __restrict__ vt,
                                              float* __restrict__ out) {
  __shared__ float e1s[8 * 516];
  __shared__ float h2s[16 * 516];
  int tid = threadIdx.x;
  int sx = blockIdx.x;
  int b = blockIdx.y;
#pragma unroll
  for (int j = 0; j < 8; ++j) {
    int idx = tid + 128 * j;
    int r = idx >> 7, c4 = idx & 127;
    float4 v = *(const float4*)(E1 + ((size_t)(sx * 8 + r) * 64 + b) * 512 + c4 * 4);
    *(float4*)&e1s[r * 516 + c4 * 4] = v;
  }
  int tl = tid >> 3, sl = tid & 7;
  for (int tt = 0; tt < 16; ++tt) {
    __syncthreads();
#pragma unroll
    for (int j = 0; j < 16; ++j) {
      int idx = tid + 128 * j;
      int r = idx >> 7, c4 = idx & 127;
      float4 v = *(const float4*)(H2 + ((size_t)(tt * 16 + r) * 64 + b) * 512 + c4 * 4);
      *(float4*)&h2s[r * 516 + c4 * 4] = v;
    }
    __syncthreads();
    float acc = 0.f;
    const float* ep = &e1s[sl * 516];
    const float* hp = &h2s[tl * 516];
#pragma unroll 8
    for (int w4 = 0; w4 < 128; ++w4) {
      float4 a = *(const float4*)(ep + w4 * 4);
      float4 h = *(const float4*)(hp + w4 * 4);
      float4 vv = *(const float4*)(vt + w4 * 4);
      float x0 = a.x + h.x, x1 = a.y + h.y, x2 = a.z + h.z, x3 = a.w + h.w;
      float t0 = fmaf(-2.f, __builtin_amdgcn_rcpf(__expf(x0 + x0) + 1.f), 1.f);
      float t1 = fmaf(-2.f, __builtin_amdgcn_rcpf(__expf(x1 + x1) + 1.f), 1.f);
      float t2 = fmaf(-2.f, __builtin_amdgcn_rcpf(__expf(x2 + x2) + 1.f), 1.f);
      float t3 = fmaf(-2.f, __builtin_amdgcn_rcpf(__expf(x3 + x3) + 1.f), 1.f);
      acc = fmaf(t0, vv.x, acc);
      acc = fmaf(t1, vv.y, acc);
      acc = fmaf(t2, vv.z, acc);
      acc = fmaf(t3, vv.w, acc);
    }
    out[((size_t)b * 256 + tt * 16 + tl) * 256 + sx * 8 + sl] = acc;
  }
}

// ---- in-place log_softmax over rows of 256 ----
__global__ __launch_bounds__(256) void logsoftmax_kernel(float* __restrict__ out) {
  __shared__ float red[256];
  int tid = threadIdx.x;
  float* row = out + (size_t)blockIdx.x * 256;
  float v = row[tid];
  red[tid] = v;
  __syncthreads();
  for (int off = 128; off > 0; off >>= 1) {
    if (tid < off) red[tid] = fmaxf(red[tid], red[tid + off]);
    __syncthreads();
  }
  float mx = red[0];
  __syncthreads();
  red[tid] = __expf(v - mx);
  __syncthreads();
  for (int off = 128; off > 0; off >>= 1) {
    if (tid < off) red[tid] += red[tid + off];
    __syncthreads();
  }
  float lse = logf(red[0]);
  row[tid] = v - mx - lse;
}

extern "C" void kernel_launch(void* const* d_in, const int* in_sizes, int n_in,
                              void* d_out, int out_size, void* d_ws, size_t ws_size,
                              hipStream_t stream) {
  (void)in_sizes; (void)n_in; (void)out_size; (void)ws_size;
  const float* x = (const float*)d_in[0];
  const float* eWih = (const float*)d_in[1];
  const float* eWhh = (const float*)d_in[2];
  const float* ebih = (const float*)d_in[3];
  const float* ebhh = (const float*)d_in[4];
  const float* dWih = (const float*)d_in[5];
  const float* dWhh = (const float*)d_in[6];
  const float* dbih = (const float*)d_in[7];
  const float* dbhh = (const float*)d_in[8];
  const float* w1 = (const float*)d_in[9];
  const float* w2 = (const float*)d_in[10];
  const float* vt = (const float*)d_in[11];
  float* out = (float*)d_out;
  float* ws = (float*)d_ws;

  // workspace (floats) — total ~28.35M floats = 113.4 MB
  float* E1 = ws;                      //  8,388,608  [S,B,W]
  float* H2 = E1 + 8388608ull;         //  8,388,608  [S,B,W]
  float* HBUF = H2 + 8388608ull;       //  8,388,608  [S,B,H] enc then dec h
  float* WTe = HBUF + 8388608ull;      //  1,572,864  [768][2048]
  float* WTd = WTe + 1572864ull;       //  1,572,864
  float* Cst = WTd + 1572864ull;       //     32,768
  unsigned int* CNT = (unsigned int*)(Cst + 32768ull);  // 8 uints

  const unsigned ldsB = (24576 + 12288 + 640) * 4;  // 150,016 B

  hipMemsetAsync(CNT, 0, 8 * sizeof(unsigned int), stream);
  transpose_w<<<dim3(16, 64), 256, 0, stream>>>(eWhh, WTe, 512);
  transpose_w<<<dim3(8, 64), 256, 0, stream>>>(eWih, WTe + 512 * 2048, 256);
  transpose_w<<<dim3(16, 64), 256, 0, stream>>>(dWhh, WTd, 512);
  transpose_w<<<dim3(8, 64), 256, 0, stream>>>(dWih, WTd + 512 * 2048, 256);

  {  // encoder chain
    const float* a0 = WTe; const float* a1 = x; const float* a2 = ebih;
    const float* a3 = ebhh; float* a4 = HBUF; float* a5 = Cst;
    unsigned int* a6 = CNT; int a7 = 1;
    void* args[] = {&a0, &a1, &a2, &a3, &a4, &a5, &a6, &a7};
    hipLaunchCooperativeKernel((const void*)lstm_chain, dim3(256), dim3(256), args,
                               ldsB, stream);
  }
  gemm_fp32<<<dim3(4, 128), 256, 0, stream>>>(HBUF, w1, E1, 512, 512);
  {  // decoder chain
    const float* a0 = WTd; const float* a1 = x; const float* a2 = dbih;
    const float* a3 = dbhh; float* a4 = HBUF; float* a5 = Cst;
    unsigned int* a6 = CNT + 4; int a7 = 0;
    void* args[] = {&a0, &a1, &a2, &a3, &a4, &a5, &a6, &a7};
    hipLaunchCooperativeKernel((const void*)lstm_chain, dim3(256), dim3(256), args,
                               ldsB, stream);
  }
  gemm_fp32<<<dim3(4, 128), 256, 0, stream>>>(HBUF, w2, H2, 512, 512);
  scorer<<<dim3(32, 64), 128, 0, stream>>>(E1, H2, vt, out);
  logsoftmax_kernel<<<16384, 256, 0, stream>>>(out);
}

// Round 4
// 7886.193 us; speedup vs baseline: 1.7445x; 1.7445x over previous
//
#include <hip/hip_runtime.h>
#include <cmath>

__device__ __forceinline__ float sigm(float x) { return 1.0f / (1.0f + __expf(-x)); }

// ---------------- tiled transpose [2048][K] -> [K][2048] ----------------
__global__ __launch_bounds__(256) void transpose_w(const float* __restrict__ in,
                                                   float* __restrict__ outT, int K) {
  __shared__ float tile[32][33];
  int tx = threadIdx.x & 31, ty = threadIdx.x >> 5;
  int k0 = blockIdx.x * 32;
  int j0 = blockIdx.y * 32;
#pragma unroll
  for (int i = 0; i < 32; i += 8)
    tile[ty + i][tx] = in[(size_t)(j0 + ty + i) * K + k0 + tx];
  __syncthreads();
#pragma unroll
  for (int i = 0; i < 32; i += 8)
    outT[(size_t)(k0 + ty + i) * 2048 + j0 + tx] = tile[tx][ty + i];
}

// ---- persistent fused LSTM chain: 256 steps in one cooperative launch ----
// Grid 256 = 4 bg x 64 ng. Block owns 16 batches x 8 hidden units (32 gate-cols).
// WT [768][2048] = [Whh^T ; Wih^T] packed; block's slice lives in LDS all steps.
// Cross-block h handoff: FENCE-FREE — relaxed agent-scope atomics (write-through to
// the coherent point) + vmcnt drain + flag. No buffer_wbl2/inv (that was the 23us/step
// cost in R3: VALUBusy 7%).
__global__ __launch_bounds__(256, 1) void lstm_chain(
    const float* __restrict__ WT, const float* __restrict__ x,
    const float* __restrict__ bih, const float* __restrict__ bhh,
    float* __restrict__ HBUF,        // [256][64][512]
    float* __restrict__ Cst,         // [64][512]
    unsigned int* __restrict__ cnt,  // [4] per-bg step counters
    int is_enc) {
  extern __shared__ float lds[];
  float4* W4 = (float4*)lds;            // 768 x 8 f4 (XOR-swizzled) = 96 KB
  float4* A4 = (float4*)(lds + 24576);  // 16 x 192 f4 (XOR-swizzled) = 48 KB
  float* gates = lds + 24576 + 12288;   // 16 x 40
  const int bg = blockIdx.x >> 6, ng = blockIdx.x & 63;
  const int tid = threadIdx.x;

  // ---- stage W slice once: logical W[k][gc], gc = gate*8 + n8, k in [0,768) ----
#pragma unroll
  for (int r = 0; r < 24; ++r) {
    int idx = tid + 256 * r;
    int k = idx >> 3, j = idx & 7;
    float4 v =
        *(const float4*)(WT + (size_t)k * 2048 + (j >> 1) * 512 + ng * 8 + (j & 1) * 4);
    W4[k * 8 + (j ^ ((k >> 2) & 7))] = v;
  }
  // ---- per-thread cell state + biases (threads 0..127 own (b,n8)) ----
  float bi_i = 0.f, bi_f = 0.f, bi_g = 0.f, bi_o = 0.f, creg = 0.f;
  if (tid < 128) {
    int b = tid >> 3, n8 = tid & 7;
    int n_g = ng * 8 + n8;
    bi_i = bih[n_g] + bhh[n_g];
    bi_f = bih[512 + n_g] + bhh[512 + n_g];
    bi_g = bih[1024 + n_g] + bhh[1024 + n_g];
    bi_o = bih[1536 + n_g] + bhh[1536 + n_g];
    if (!is_enc) creg = Cst[(size_t)(bg * 16 + b) * 512 + n_g];
  }
  // ---- initial A: h0 (zeros for encoder, HBUF row 255 for decoder) + x_0 ----
#pragma unroll
  for (int r = 0; r < 8; ++r) {
    int idx = tid + 256 * r;
    int b = idx >> 7, q = idx & 127;
    float4 v;
    if (is_enc)
      v = make_float4(0.f, 0.f, 0.f, 0.f);
    else
      v = *(const float4*)(HBUF + ((size_t)(255 * 64) + bg * 16 + b) * 512 + 4 * q);
    A4[b * 192 + (q ^ ((b >> 1) & 7))] = v;
  }
#pragma unroll
  for (int r = 0; r < 4; ++r) {
    int idx = tid + 256 * r;
    int b = idx >> 6, q = idx & 63;
    float4 v = *(const float4*)(x + ((size_t)(bg * 16 + b) * 256 + 0) * 256 + 4 * q);
    A4[b * 192 + ((128 + q) ^ ((b >> 1) & 7))] = v;
  }
  __syncthreads();

  const int w = tid >> 6;  // wave = gate (0:i 1:f 2:g 3:o)
  const int lane = tid & 63;
  const int kq = lane >> 3, b8 = lane & 7;
  const int b0 = 2 * b8, b1 = b0 + 1;
  const int jlo = (2 * w) ^ kq, jhi = (2 * w + 1) ^ kq;
  const int kqx = kq ^ b8;  // A phys low-3 for this thread's batches

  for (int t = 0; t < 256; ++t) {
    float acc0[8], acc1[8];
#pragma unroll
    for (int g = 0; g < 8; ++g) { acc0[g] = 0.f; acc1[g] = 0.f; }
#pragma unroll 2
    for (int j = 0; j < 24; ++j) {
      int qa = (j << 3) + kqx;
      float4 a0 = A4[b0 * 192 + qa];
      float4 a1 = A4[b1 * 192 + qa];
      int wr = ((j << 3) + kq) << 2;  // k = 4q
      float a0v[4] = {a0.x, a0.y, a0.z, a0.w};
      float a1v[4] = {a1.x, a1.y, a1.z, a1.w};
#pragma unroll
      for (int i = 0; i < 4; ++i) {
        float4 wlo = W4[(wr + i) * 8 + jlo];
        float4 whi = W4[(wr + i) * 8 + jhi];
        acc0[0] = fmaf(a0v[i], wlo.x, acc0[0]);
        acc0[1] = fmaf(a0v[i], wlo.y, acc0[1]);
        acc0[2] = fmaf(a0v[i], wlo.z, acc0[2]);
        acc0[3] = fmaf(a0v[i], wlo.w, acc0[3]);
        acc0[4] = fmaf(a0v[i], whi.x, acc0[4]);
        acc0[5] = fmaf(a0v[i], whi.y, acc0[5]);
        acc0[6] = fmaf(a0v[i], whi.z, acc0[6]);
        acc0[7] = fmaf(a0v[i], whi.w, acc0[7]);
        acc1[0] = fmaf(a1v[i], wlo.x, acc1[0]);
        acc1[1] = fmaf(a1v[i], wlo.y, acc1[1]);
        acc1[2] = fmaf(a1v[i], wlo.z, acc1[2]);
        acc1[3] = fmaf(a1v[i], wlo.w, acc1[3]);
        acc1[4] = fmaf(a1v[i], whi.x, acc1[4]);
        acc1[5] = fmaf(a1v[i], whi.y, acc1[5]);
        acc1[6] = fmaf(a1v[i], whi.z, acc1[6]);
        acc1[7] = fmaf(a1v[i], whi.w, acc1[7]);
      }
    }
    // reduce over kq (lane-stride 8,16,32)
#pragma unroll
    for (int d = 8; d <= 32; d <<= 1) {
#pragma unroll
      for (int g = 0; g < 8; ++g) {
        acc0[g] += __shfl_xor(acc0[g], d, 64);
        acc1[g] += __shfl_xor(acc1[g], d, 64);
      }
    }
    if (kq == 0) {
#pragma unroll
      for (int g = 0; g < 8; ++g) {
        gates[b0 * 40 + w * 8 + g] = acc0[g];
        gates[b1 * 40 + w * 8 + g] = acc1[g];
      }
    }
    __syncthreads();
    // ---- cell update + h store (agent-scope write-through, no fence) ----
    if (tid < 128) {
      int b = tid >> 3, n8 = tid & 7;
      float pi = gates[b * 40 + n8] + bi_i;
      float pf = gates[b * 40 + 8 + n8] + bi_f;
      float pg = gates[b * 40 + 16 + n8] + bi_g;
      float po = gates[b * 40 + 24 + n8] + bi_o;
      float ig = sigm(pi), fg = sigm(pf), gg = tanhf(pg), og = sigm(po);
      float cn = fmaf(fg, creg, ig * gg);
      if (is_enc) creg = cn;  // decoder: cell pinned at cT
      float hn = og * tanhf(cn);
      float* hp = HBUF + ((size_t)t * 64 + bg * 16 + b) * 512 + ng * 8 + n8;
      __hip_atomic_store(hp, hn, __ATOMIC_RELAXED, __HIP_MEMORY_SCOPE_AGENT);
      if (is_enc && t == 255) Cst[(size_t)(bg * 16 + b) * 512 + ng * 8 + n8] = cn;
    }
    if (t < 255) {
      // drain own stores to the coherent point, then block-wide barrier:
      // all of this block's h is globally visible before the flag bump.
      asm volatile("s_waitcnt vmcnt(0)" ::: "memory");
      __syncthreads();
      if (tid == 0)  // fire-and-forget release of this block's contribution
        __hip_atomic_fetch_add(cnt + bg, 1u, __ATOMIC_RELAXED,
                               __HIP_MEMORY_SCOPE_AGENT);
      // x_{t+1} restage overlaps the spin window (flag-independent, cached)
#pragma unroll
      for (int r = 0; r < 4; ++r) {
        int idx = tid + 256 * r;
        int b = idx >> 6, q = idx & 63;
        float4 v =
            *(const float4*)(x + ((size_t)(bg * 16 + b) * 256 + (t + 1)) * 256 + 4 * q);
        A4[b * 192 + ((128 + q) ^ ((b >> 1) & 7))] = v;
      }
      if (tid == 0) {
        unsigned tgt = 64u * (unsigned)(t + 1);
        while (__hip_atomic_load(cnt + bg, __ATOMIC_RELAXED,
                                 __HIP_MEMORY_SCOPE_AGENT) < tgt)
          __builtin_amdgcn_s_sleep(2);
      }
      __syncthreads();
      // ---- h restage: agent-scope loads (bypass stale L1/L2, read L3) ----
      float* hb = HBUF + (size_t)t * 64 * 512;
#pragma unroll
      for (int r = 0; r < 8; ++r) {
        int idx = tid + 256 * r;
        int b = idx >> 7, q = idx & 127;
        float* hp = hb + ((size_t)(bg * 16 + b)) * 512 + 4 * q;
        float4 v;
        v.x = __hip_atomic_load(hp + 0, __ATOMIC_RELAXED, __HIP_MEMORY_SCOPE_AGENT);
        v.y = __hip_atomic_load(hp + 1, __ATOMIC_RELAXED, __HIP_MEMORY_SCOPE_AGENT);
        v.z = __hip_atomic_load(hp + 2, __ATOMIC_RELAXED, __HIP_MEMORY_SCOPE_AGENT);
        v.w = __hip_atomic_load(hp + 3, __ATOMIC_RELAXED, __HIP_MEMORY_SCOPE_AGENT);
        A4[b * 192 + (q ^ ((b >> 1) & 7))] = v;
      }
      __syncthreads();
    }
  }
}

// ---- GEMM: C[r,n] = sum_k A[r][k] * W[n,k] ; 128x128 tile, 8x8 micro ----
__global__ __launch_bounds__(256) void gemm_fp32(const float* __restrict__ A,
                                                 const float* __restrict__ W,
                                                 float* __restrict__ C, int N, int K) {
  __shared__ float As[16 * 132];
  __shared__ float Ws[16 * 132];
  int tid = threadIdx.x;
  int n0 = blockIdx.x * 128, m0 = blockIdx.y * 128;
  int row = tid >> 1;
  int kbase = (tid & 1) * 8;
  const float* ap = A + (size_t)(m0 + row) * K;
  const float* wp = W + (size_t)(n0 + row) * K;
  int ty = tid >> 4, tx = tid & 15;
  float acc[8][8];
#pragma unroll
  for (int i = 0; i < 8; ++i)
#pragma unroll
    for (int j = 0; j < 8; ++j) acc[i][j] = 0.f;

  for (int kt = 0; kt < K; kt += 16) {
    float4 va0 = *(const float4*)(ap + kt + kbase);
    float4 va1 = *(const float4*)(ap + kt + kbase + 4);
    float4 vw0 = *(const float4*)(wp + kt + kbase);
    float4 vw1 = *(const float4*)(wp + kt + kbase + 4);
    __syncthreads();
    As[(kbase + 0) * 132 + row] = va0.x;
    As[(kbase + 1) * 132 + row] = va0.y;
    As[(kbase + 2) * 132 + row] = va0.z;
    As[(kbase + 3) * 132 + row] = va0.w;
    As[(kbase + 4) * 132 + row] = va1.x;
    As[(kbase + 5) * 132 + row] = va1.y;
    As[(kbase + 6) * 132 + row] = va1.z;
    As[(kbase + 7) * 132 + row] = va1.w;
    Ws[(kbase + 0) * 132 + row] = vw0.x;
    Ws[(kbase + 1) * 132 + row] = vw0.y;
    Ws[(kbase + 2) * 132 + row] = vw0.z;
    Ws[(kbase + 3) * 132 + row] = vw0.w;
    Ws[(kbase + 4) * 132 + row] = vw1.x;
    Ws[(kbase + 5) * 132 + row] = vw1.y;
    Ws[(kbase + 6) * 132 + row] = vw1.z;
    Ws[(kbase + 7) * 132 + row] = vw1.w;
    __syncthreads();
#pragma unroll
    for (int kk = 0; kk < 16; ++kk) {
      float4 a0 = *(const float4*)&As[kk * 132 + ty * 8];
      float4 a1 = *(const float4*)&As[kk * 132 + ty * 8 + 4];
      float4 w0 = *(const float4*)&Ws[kk * 132 + tx * 8];
      float4 w1 = *(const float4*)&Ws[kk * 132 + tx * 8 + 4];
      float av[8] = {a0.x, a0.y, a0.z, a0.w, a1.x, a1.y, a1.z, a1.w};
      float wv[8] = {w0.x, w0.y, w0.z, w0.w, w1.x, w1.y, w1.z, w1.w};
#pragma unroll
      for (int i = 0; i < 8; ++i)
#pragma unroll
        for (int j = 0; j < 8; ++j) acc[i][j] = fmaf(av[i], wv[j], acc[i][j]);
    }
  }
#pragma unroll
  for (int i = 0; i < 8; ++i) {
    float* cp = C + (size_t)(m0 + ty * 8 + i) * N + n0 + tx * 8;
    *(float4*)cp = make_float4(acc[i][0], acc[i][1], acc[i][2], acc[i][3]);
    *(float4*)(cp + 4) = make_float4(acc[i][4], acc[i][5], acc[i][6], acc[i][7]);
  }
}

// ---- scorer: out[b,t,s] = sum_w vt[w]*tanh(e1[s,b,w] + H2[t,b,w]) ----
__global__ __launch_bounds__(128) void scorer(const float* __restrict__ E1,
                                              const float* __restrict__ H2,
                                              const float* __restrict__ vt,
                                              float* __restrict__ out) {
  __shared__ float e1s[8 * 516];
  __shared__ float h2s[16 * 516];
  int tid = threadIdx.x;
  int sx = blockIdx.x;
  int b = blockIdx.y;
#pragma unroll
  for (int j = 0; j < 8; ++j) {
    int idx = tid + 128 * j;
    int r = idx >> 7, c4 = idx & 127;
    float4 v = *(const float4*)(E1 + ((size_t)(sx * 8 + r) * 64 + b) * 512 + c4 * 4);
    *(float4*)&e1s[r * 516 + c4 * 4] = v;
  }
  int tl = tid >> 3, sl = tid & 7;
  for (int tt = 0; tt < 16; ++tt) {
    __syncthreads();
#pragma unroll
    for (int j = 0; j < 16; ++j) {
      int idx = tid + 128 * j;
      int r = idx >> 7, c4 = idx & 127;
      float4 v = *(const float4*)(H2 + ((size_t)(tt * 16 + r) * 64 + b) * 512 + c4 * 4);
      *(float4*)&h2s[r * 516 + c4 * 4] = v;
    }
    __syncthreads();
    float acc = 0.f;
    const float* ep = &e1s[sl * 516];
    const float* hp = &h2s[tl * 516];
#pragma unroll 8
    for (int w4 = 0; w4 < 128; ++w4) {
      float4 a = *(const float4*)(ep + w4 * 4);
      float4 h = *(const float4*)(hp + w4 * 4);
      float4 vv = *(const float4*)(vt + w4 * 4);
      float x0 = a.x + h.x, x1 = a.y + h.y, x2 = a.z + h.z, x3 = a.w + h.w;
      float t0 = fmaf(-2.f, __builtin_amdgcn_rcpf(__expf(x0 + x0) + 1.f), 1.f);
      float t1 = fmaf(-2.f, __builtin_amdgcn_rcpf(__expf(x1 + x1) + 1.f), 1.f);
      float t2 = fmaf(-2.f, __builtin_amdgcn_rcpf(__expf(x2 + x2) + 1.f), 1.f);
      float t3 = fmaf(-2.f, __builtin_amdgcn_rcpf(__expf(x3 + x3) + 1.f), 1.f);
      acc = fmaf(t0, vv.x, acc);
      acc = fmaf(t1, vv.y, acc);
      acc = fmaf(t2, vv.z, acc);
      acc = fmaf(t3, vv.w, acc);
    }
    out[((size_t)b * 256 + tt * 16 + tl) * 256 + sx * 8 + sl] = acc;
  }
}

// ---- in-place log_softmax over rows of 256 ----
__global__ __launch_bounds__(256) void logsoftmax_kernel(float* __restrict__ out) {
  __shared__ float red[256];
  int tid = threadIdx.x;
  float* row = out + (size_t)blockIdx.x * 256;
  float v = row[tid];
  red[tid] = v;
  __syncthreads();
  for (int off = 128; off > 0; off >>= 1) {
    if (tid < off) red[tid] = fmaxf(red[tid], red[tid + off]);
    __syncthreads();
  }
  float mx = red[0];
  __syncthreads();
  red[tid] = __expf(v - mx);
  __syncthreads();
  for (int off = 128; off > 0; off >>= 1) {
    if (tid < off) red[tid] += red[tid + off];
    __syncthreads();
  }
  float lse = logf(red[0]);
  row[tid] = v - mx - lse;
}

extern "C" void kernel_launch(void* const* d_in, const int* in_sizes, int n_in,
                              void* d_out, int out_size, void* d_ws, size_t ws_size,
                              hipStream_t stream) {
  (void)in_sizes; (void)n_in; (void)out_size; (void)ws_size;
  const float* x = (const float*)d_in[0];
  const float* eWih = (const float*)d_in[1];
  const float* eWhh = (const float*)d_in[2];
  const float* ebih = (const float*)d_in[3];
  const float* ebhh = (const float*)d_in[4];
  const float* dWih = (const float*)d_in[5];
  const float* dWhh = (const float*)d_in[6];
  const float* dbih = (const float*)d_in[7];
  const float* dbhh = (const float*)d_in[8];
  const float* w1 = (const float*)d_in[9];
  const float* w2 = (const float*)d_in[10];
  const float* vt = (const float*)d_in[11];
  float* out = (float*)d_out;
  float* ws = (float*)d_ws;

  // workspace (floats) — total ~28.35M floats = 113.4 MB
  float* E1 = ws;                  //  8,388,608  [S,B,W]
  float* H2 = E1 + 8388608ull;     //  8,388,608  [S,B,W]
  float* HBUF = H2 + 8388608ull;   //  8,388,608  [S,B,H] enc then dec h
  float* WTe = HBUF + 8388608ull;  //  1,572,864  [768][2048]
  float* WTd = WTe + 1572864ull;   //  1,572,864
  float* Cst = WTd + 1572864ull;   //     32,768
  unsigned int* CNT = (unsigned int*)(Cst + 32768ull);  // 8 uints

  const unsigned ldsB = (24576 + 12288 + 640) * 4;  // 150,016 B

  hipMemsetAsync(CNT, 0, 8 * sizeof(unsigned int), stream);
  transpose_w<<<dim3(16, 64), 256, 0, stream>>>(eWhh, WTe, 512);
  transpose_w<<<dim3(8, 64), 256, 0, stream>>>(eWih, WTe + 512 * 2048, 256);
  transpose_w<<<dim3(16, 64), 256, 0, stream>>>(dWhh, WTd, 512);
  transpose_w<<<dim3(8, 64), 256, 0, stream>>>(dWih, WTd + 512 * 2048, 256);

  {  // encoder chain
    const float* a0 = WTe; const float* a1 = x; const float* a2 = ebih;
    const float* a3 = ebhh; float* a4 = HBUF; float* a5 = Cst;
    unsigned int* a6 = CNT; int a7 = 1;
    void* args[] = {&a0, &a1, &a2, &a3, &a4, &a5, &a6, &a7};
    hipLaunchCooperativeKernel((const void*)lstm_chain, dim3(256), dim3(256), args,
                               ldsB, stream);
  }
  gemm_fp32<<<dim3(4, 128), 256, 0, stream>>>(HBUF, w1, E1, 512, 512);
  {  // decoder chain
    const float* a0 = WTd; const float* a1 = x; const float* a2 = dbih;
    const float* a3 = dbhh; float* a4 = HBUF; float* a5 = Cst;
    unsigned int* a6 = CNT + 4; int a7 = 0;
    void* args[] = {&a0, &a1, &a2, &a3, &a4, &a5, &a6, &a7};
    hipLaunchCooperativeKernel((const void*)lstm_chain, dim3(256), dim3(256), args,
                               ldsB, stream);
  }
  gemm_fp32<<<dim3(4, 128), 256, 0, stream>>>(HBUF, w2, H2, 512, 512);
  scorer<<<dim3(32, 64), 128, 0, stream>>>(E1, H2, vt, out);
  logsoftmax_kernel<<<16384, 256, 0, stream>>>(out);
}

// Round 5
// 4715.077 us; speedup vs baseline: 2.9178x; 1.6725x over previous
//
#include <hip/hip_runtime.h>
#include <cmath>

__device__ __forceinline__ float sigm(float x) { return 1.0f / (1.0f + __expf(-x)); }

// ---------------- tiled transpose [2048][K] -> [K][2048] ----------------
__global__ __launch_bounds__(256) void transpose_w(const float* __restrict__ in,
                                                   float* __restrict__ outT, int K) {
  __shared__ float tile[32][33];
  int tx = threadIdx.x & 31, ty = threadIdx.x >> 5;
  int k0 = blockIdx.x * 32;
  int j0 = blockIdx.y * 32;
#pragma unroll
  for (int i = 0; i < 32; i += 8)
    tile[ty + i][tx] = in[(size_t)(j0 + ty + i) * K + k0 + tx];
  __syncthreads();
#pragma unroll
  for (int i = 0; i < 32; i += 8)
    outT[(size_t)(k0 + ty + i) * 2048 + j0 + tx] = tile[tx][ty + i];
}

// ---- persistent fused LSTM chain: 256 steps in one cooperative launch ----
// Grid 256 = 4 bg x 64 ng. Block owns 16 batches x 8 hidden units (32 gate-cols).
// WT [768][2048] = [Whh^T ; Wih^T] packed; block's slice lives in LDS all steps.
// Barrier (R5): arrival counter and release word on SEPARATE 512B-spaced lines.
// R4's single line mixed 256 RMWs + continuous polls -> L3 line saturation
// (~11.5us/step). Now: 64 RMWs on arr line (no polls), polls only on rel line.
// No fences: data drained to coherent point before flag ops issue.
__global__ __launch_bounds__(256, 1) void lstm_chain(
    const float* __restrict__ WT, const float* __restrict__ x,
    const float* __restrict__ bih, const float* __restrict__ bhh,
    float* __restrict__ HBUF,        // [256][64][512]
    float* __restrict__ Cst,         // [64][512]
    unsigned int* __restrict__ cnt,  // per-chain: 4 domains x 128 uints
    int is_enc) {
  extern __shared__ float lds[];
  float4* W4 = (float4*)lds;            // 768 x 8 f4 (XOR-swizzled) = 96 KB
  float4* A4 = (float4*)(lds + 24576);  // 16 x 192 f4 (XOR-swizzled) = 48 KB
  float* gates = lds + 24576 + 12288;   // 16 x 40
  const int bg = blockIdx.x >> 6, ng = blockIdx.x & 63;
  const int tid = threadIdx.x;
  unsigned int* arr = cnt + bg * 128;       // arrival counter (own line)
  unsigned int* rel = cnt + bg * 128 + 64;  // release word (own line, +256B)

  // ---- stage W slice once: logical W[k][gc], gc = gate*8 + n8, k in [0,768) ----
#pragma unroll
  for (int r = 0; r < 24; ++r) {
    int idx = tid + 256 * r;
    int k = idx >> 3, j = idx & 7;
    float4 v =
        *(const float4*)(WT + (size_t)k * 2048 + (j >> 1) * 512 + ng * 8 + (j & 1) * 4);
    W4[k * 8 + (j ^ ((k >> 2) & 7))] = v;
  }
  // ---- per-thread cell state + biases (threads 0..127 own (b,n8)) ----
  float bi_i = 0.f, bi_f = 0.f, bi_g = 0.f, bi_o = 0.f, creg = 0.f;
  if (tid < 128) {
    int b = tid >> 3, n8 = tid & 7;
    int n_g = ng * 8 + n8;
    bi_i = bih[n_g] + bhh[n_g];
    bi_f = bih[512 + n_g] + bhh[512 + n_g];
    bi_g = bih[1024 + n_g] + bhh[1024 + n_g];
    bi_o = bih[1536 + n_g] + bhh[1536 + n_g];
    if (!is_enc) creg = Cst[(size_t)(bg * 16 + b) * 512 + n_g];
  }
  // ---- initial A: h0 (zeros for encoder, HBUF row 255 for decoder) + x_0 ----
#pragma unroll
  for (int r = 0; r < 8; ++r) {
    int idx = tid + 256 * r;
    int b = idx >> 7, q = idx & 127;
    float4 v;
    if (is_enc)
      v = make_float4(0.f, 0.f, 0.f, 0.f);
    else
      v = *(const float4*)(HBUF + ((size_t)(255 * 64) + bg * 16 + b) * 512 + 4 * q);
    A4[b * 192 + (q ^ ((b >> 1) & 7))] = v;
  }
#pragma unroll
  for (int r = 0; r < 4; ++r) {
    int idx = tid + 256 * r;
    int b = idx >> 6, q = idx & 63;
    float4 v = *(const float4*)(x + ((size_t)(bg * 16 + b) * 256 + 0) * 256 + 4 * q);
    A4[b * 192 + ((128 + q) ^ ((b >> 1) & 7))] = v;
  }
  __syncthreads();

  const int w = tid >> 6;  // wave = gate (0:i 1:f 2:g 3:o)
  const int lane = tid & 63;
  const int kq = lane >> 3, b8 = lane & 7;
  const int b0 = 2 * b8, b1 = b0 + 1;
  const int jlo = (2 * w) ^ kq, jhi = (2 * w + 1) ^ kq;
  const int kqx = kq ^ b8;  // A phys low-3 for this thread's batches

  for (int t = 0; t < 256; ++t) {
    float acc0[8], acc1[8];
#pragma unroll
    for (int g = 0; g < 8; ++g) { acc0[g] = 0.f; acc1[g] = 0.f; }
#pragma unroll 2
    for (int j = 0; j < 24; ++j) {
      int qa = (j << 3) + kqx;
      float4 a0 = A4[b0 * 192 + qa];
      float4 a1 = A4[b1 * 192 + qa];
      int wr = ((j << 3) + kq) << 2;  // k = 4q
      float a0v[4] = {a0.x, a0.y, a0.z, a0.w};
      float a1v[4] = {a1.x, a1.y, a1.z, a1.w};
#pragma unroll
      for (int i = 0; i < 4; ++i) {
        float4 wlo = W4[(wr + i) * 8 + jlo];
        float4 whi = W4[(wr + i) * 8 + jhi];
        acc0[0] = fmaf(a0v[i], wlo.x, acc0[0]);
        acc0[1] = fmaf(a0v[i], wlo.y, acc0[1]);
        acc0[2] = fmaf(a0v[i], wlo.z, acc0[2]);
        acc0[3] = fmaf(a0v[i], wlo.w, acc0[3]);
        acc0[4] = fmaf(a0v[i], whi.x, acc0[4]);
        acc0[5] = fmaf(a0v[i], whi.y, acc0[5]);
        acc0[6] = fmaf(a0v[i], whi.z, acc0[6]);
        acc0[7] = fmaf(a0v[i], whi.w, acc0[7]);
        acc1[0] = fmaf(a1v[i], wlo.x, acc1[0]);
        acc1[1] = fmaf(a1v[i], wlo.y, acc1[1]);
        acc1[2] = fmaf(a1v[i], wlo.z, acc1[2]);
        acc1[3] = fmaf(a1v[i], wlo.w, acc1[3]);
        acc1[4] = fmaf(a1v[i], whi.x, acc1[4]);
        acc1[5] = fmaf(a1v[i], whi.y, acc1[5]);
        acc1[6] = fmaf(a1v[i], whi.z, acc1[6]);
        acc1[7] = fmaf(a1v[i], whi.w, acc1[7]);
      }
    }
    // reduce over kq (lane-stride 8,16,32)
#pragma unroll
    for (int d = 8; d <= 32; d <<= 1) {
#pragma unroll
      for (int g = 0; g < 8; ++g) {
        acc0[g] += __shfl_xor(acc0[g], d, 64);
        acc1[g] += __shfl_xor(acc1[g], d, 64);
      }
    }
    if (kq == 0) {
#pragma unroll
      for (int g = 0; g < 8; ++g) {
        gates[b0 * 40 + w * 8 + g] = acc0[g];
        gates[b1 * 40 + w * 8 + g] = acc1[g];
      }
    }
    __syncthreads();
    // ---- cell update + h store (agent-scope write-through, no fence) ----
    if (tid < 128) {
      int b = tid >> 3, n8 = tid & 7;
      float pi = gates[b * 40 + n8] + bi_i;
      float pf = gates[b * 40 + 8 + n8] + bi_f;
      float pg = gates[b * 40 + 16 + n8] + bi_g;
      float po = gates[b * 40 + 24 + n8] + bi_o;
      float ig = sigm(pi), fg = sigm(pf), gg = tanhf(pg), og = sigm(po);
      float cn = fmaf(fg, creg, ig * gg);
      if (is_enc) creg = cn;  // decoder: cell pinned at cT
      float hn = og * tanhf(cn);
      float* hp = HBUF + ((size_t)t * 64 + bg * 16 + b) * 512 + ng * 8 + n8;
      __hip_atomic_store(hp, hn, __ATOMIC_RELAXED, __HIP_MEMORY_SCOPE_AGENT);
      if (is_enc && t == 255) Cst[(size_t)(bg * 16 + b) * 512 + ng * 8 + n8] = cn;
    }
    if (t < 255) {
      // all h of this block globally visible before the arrival bump
      asm volatile("s_waitcnt vmcnt(0)" ::: "memory");
      __syncthreads();
      unsigned old = 0;
      const unsigned tgt = 64u * (unsigned)(t + 1);
      if (tid == 0)
        old = __hip_atomic_fetch_add(arr, 1u, __ATOMIC_RELAXED,
                                     __HIP_MEMORY_SCOPE_AGENT);
      // x_{t+1} restage overlaps the wait window (flag-independent, cached)
#pragma unroll
      for (int r = 0; r < 4; ++r) {
        int idx = tid + 256 * r;
        int b = idx >> 6, q = idx & 63;
        float4 v =
            *(const float4*)(x + ((size_t)(bg * 16 + b) * 256 + (t + 1)) * 256 + 4 * q);
        A4[b * 192 + ((128 + q) ^ ((b >> 1) & 7))] = v;
      }
      if (tid == 0) {
        if (old == tgt - 1u) {  // last arrival releases the step
          __hip_atomic_store(rel, tgt, __ATOMIC_RELAXED, __HIP_MEMORY_SCOPE_AGENT);
        } else {
          while (__hip_atomic_load(rel, __ATOMIC_RELAXED, __HIP_MEMORY_SCOPE_AGENT) <
                 tgt)
            __builtin_amdgcn_s_sleep(1);
        }
      }
      __syncthreads();
      // ---- h restage: plain vectorized loads (first touch; writers bypassed L2,
      // dispatch-start acquire invalidated ours -> no staleness) ----
      const float4* hb = (const float4*)(HBUF + (size_t)t * 64 * 512);
#pragma unroll
      for (int r = 0; r < 8; ++r) {
        int idx = tid + 256 * r;
        int b = idx >> 7, q = idx & 127;
        float4 v = hb[(size_t)(bg * 16 + b) * 128 + q];
        A4[b * 192 + (q ^ ((b >> 1) & 7))] = v;
      }
      __syncthreads();
    }
  }
}

// ---- GEMM: C[r,n] = sum_k A[r][k] * W[n,k] ; 128x128 tile, 8x8 micro ----
__global__ __launch_bounds__(256) void gemm_fp32(const float* __restrict__ A,
                                                 const float* __restrict__ W,
                                                 float* __restrict__ C, int N, int K) {
  __shared__ float As[16 * 132];
  __shared__ float Ws[16 * 132];
  int tid = threadIdx.x;
  int n0 = blockIdx.x * 128, m0 = blockIdx.y * 128;
  int row = tid >> 1;
  int kbase = (tid & 1) * 8;
  const float* ap = A + (size_t)(m0 + row) * K;
  const float* wp = W + (size_t)(n0 + row) * K;
  int ty = tid >> 4, tx = tid & 15;
  float acc[8][8];
#pragma unroll
  for (int i = 0; i < 8; ++i)
#pragma unroll
    for (int j = 0; j < 8; ++j) acc[i][j] = 0.f;

  for (int kt = 0; kt < K; kt += 16) {
    float4 va0 = *(const float4*)(ap + kt + kbase);
    float4 va1 = *(const float4*)(ap + kt + kbase + 4);
    float4 vw0 = *(const float4*)(wp + kt + kbase);
    float4 vw1 = *(const float4*)(wp + kt + kbase + 4);
    __syncthreads();
    As[(kbase + 0) * 132 + row] = va0.x;
    As[(kbase + 1) * 132 + row] = va0.y;
    As[(kbase + 2) * 132 + row] = va0.z;
    As[(kbase + 3) * 132 + row] = va0.w;
    As[(kbase + 4) * 132 + row] = va1.x;
    As[(kbase + 5) * 132 + row] = va1.y;
    As[(kbase + 6) * 132 + row] = va1.z;
    As[(kbase + 7) * 132 + row] = va1.w;
    Ws[(kbase + 0) * 132 + row] = vw0.x;
    Ws[(kbase + 1) * 132 + row] = vw0.y;
    Ws[(kbase + 2) * 132 + row] = vw0.z;
    Ws[(kbase + 3) * 132 + row] = vw0.w;
    Ws[(kbase + 4) * 132 + row] = vw1.x;
    Ws[(kbase + 5) * 132 + row] = vw1.y;
    Ws[(kbase + 6) * 132 + row] = vw1.z;
    Ws[(kbase + 7) * 132 + row] = vw1.w;
    __syncthreads();
#pragma unroll
    for (int kk = 0; kk < 16; ++kk) {
      float4 a0 = *(const float4*)&As[kk * 132 + ty * 8];
      float4 a1 = *(const float4*)&As[kk * 132 + ty * 8 + 4];
      float4 w0 = *(const float4*)&Ws[kk * 132 + tx * 8];
      float4 w1 = *(const float4*)&Ws[kk * 132 + tx * 8 + 4];
      float av[8] = {a0.x, a0.y, a0.z, a0.w, a1.x, a1.y, a1.z, a1.w};
      float wv[8] = {w0.x, w0.y, w0.z, w0.w, w1.x, w1.y, w1.z, w1.w};
#pragma unroll
      for (int i = 0; i < 8; ++i)
#pragma unroll
        for (int j = 0; j < 8; ++j) acc[i][j] = fmaf(av[i], wv[j], acc[i][j]);
    }
  }
#pragma unroll
  for (int i = 0; i < 8; ++i) {
    float* cp = C + (size_t)(m0 + ty * 8 + i) * N + n0 + tx * 8;
    *(float4*)cp = make_float4(acc[i][0], acc[i][1], acc[i][2], acc[i][3]);
    *(float4*)(cp + 4) = make_float4(acc[i][4], acc[i][5], acc[i][6], acc[i][7]);
  }
}

// ---- scorer: out[b,t,s] = sum_w vt[w]*tanh(e1[s,b,w] + H2[t,b,w]) ----
__global__ __launch_bounds__(128) void scorer(const float* __restrict__ E1,
                                              const float* __restrict__ H2,
                                              const float* __restrict__ vt,
                                              float* __restrict__ out) {
  __shared__ float e1s[8 * 516];
  __shared__ float h2s[16 * 516];
  int tid = threadIdx.x;
  int sx = blockIdx.x;
  int b = blockIdx.y;
#pragma unroll
  for (int j = 0; j < 8; ++j) {
    int idx = tid + 128 * j;
    int r = idx >> 7, c4 = idx & 127;
    float4 v = *(const float4*)(E1 + ((size_t)(sx * 8 + r) * 64 + b) * 512 + c4 * 4);
    *(float4*)&e1s[r * 516 + c4 * 4] = v;
  }
  int tl = tid >> 3, sl = tid & 7;
  for (int tt = 0; tt < 16; ++tt) {
    __syncthreads();
#pragma unroll
    for (int j = 0; j < 16; ++j) {
      int idx = tid + 128 * j;
      int r = idx >> 7, c4 = idx & 127;
      float4 v = *(const float4*)(H2 + ((size_t)(tt * 16 + r) * 64 + b) * 512 + c4 * 4);
      *(float4*)&h2s[r * 516 + c4 * 4] = v;
    }
    __syncthreads();
    float acc = 0.f;
    const float* ep = &e1s[sl * 516];
    const float* hp = &h2s[tl * 516];
#pragma unroll 8
    for (int w4 = 0; w4 < 128; ++w4) {
      float4 a = *(const float4*)(ep + w4 * 4);
      float4 h = *(const float4*)(hp + w4 * 4);
      float4 vv = *(const float4*)(vt + w4 * 4);
      float x0 = a.x + h.x, x1 = a.y + h.y, x2 = a.z + h.z, x3 = a.w + h.w;
      float t0 = fmaf(-2.f, __builtin_amdgcn_rcpf(__expf(x0 + x0) + 1.f), 1.f);
      float t1 = fmaf(-2.f, __builtin_amdgcn_rcpf(__expf(x1 + x1) + 1.f), 1.f);
      float t2 = fmaf(-2.f, __builtin_amdgcn_rcpf(__expf(x2 + x2) + 1.f), 1.f);
      float t3 = fmaf(-2.f, __builtin_amdgcn_rcpf(__expf(x3 + x3) + 1.f), 1.f);
      acc = fmaf(t0, vv.x, acc);
      acc = fmaf(t1, vv.y, acc);
      acc = fmaf(t2, vv.z, acc);
      acc = fmaf(t3, vv.w, acc);
    }
    out[((size_t)b * 256 + tt * 16 + tl) * 256 + sx * 8 + sl] = acc;
  }
}

// ---- in-place log_softmax over rows of 256 ----
__global__ __launch_bounds__(256) void logsoftmax_kernel(float* __restrict__ out) {
  __shared__ float red[256];
  int tid = threadIdx.x;
  float* row = out + (size_t)blockIdx.x * 256;
  float v = row[tid];
  red[tid] = v;
  __syncthreads();
  for (int off = 128; off > 0; off >>= 1) {
    if (tid < off) red[tid] = fmaxf(red[tid], red[tid + off]);
    __syncthreads();
  }
  float mx = red[0];
  __syncthreads();
  red[tid] = __expf(v - mx);
  __syncthreads();
  for (int off = 128; off > 0; off >>= 1) {
    if (tid < off) red[tid] += red[tid + off];
    __syncthreads();
  }
  float lse = logf(red[0]);
  row[tid] = v - mx - lse;
}

extern "C" void kernel_launch(void* const* d_in, const int* in_sizes, int n_in,
                              void* d_out, int out_size, void* d_ws, size_t ws_size,
                              hipStream_t stream) {
  (void)in_sizes; (void)n_in; (void)out_size; (void)ws_size;
  const float* x = (const float*)d_in[0];
  const float* eWih = (const float*)d_in[1];
  const float* eWhh = (const float*)d_in[2];
  const float* ebih = (const float*)d_in[3];
  const float* ebhh = (const float*)d_in[4];
  const float* dWih = (const float*)d_in[5];
  const float* dWhh = (const float*)d_in[6];
  const float* dbih = (const float*)d_in[7];
  const float* dbhh = (const float*)d_in[8];
  const float* w1 = (const float*)d_in[9];
  const float* w2 = (const float*)d_in[10];
  const float* vt = (const float*)d_in[11];
  float* out = (float*)d_out;
  float* ws = (float*)d_ws;

  // workspace (floats) — total ~28.35M floats = 113.4 MB
  float* E1 = ws;                  //  8,388,608  [S,B,W]
  float* H2 = E1 + 8388608ull;     //  8,388,608  [S,B,W]
  float* HBUF = H2 + 8388608ull;   //  8,388,608  [S,B,H] enc then dec h
  float* WTe = HBUF + 8388608ull;  //  1,572,864  [768][2048]
  float* WTd = WTe + 1572864ull;   //  1,572,864
  float* Cst = WTd + 1572864ull;   //     32,768
  unsigned int* CNT = (unsigned int*)(Cst + 32768ull);  // 1024 uints (4KB), padded

  const unsigned ldsB = (24576 + 12288 + 640) * 4;  // 150,016 B

  hipMemsetAsync(CNT, 0, 1024 * sizeof(unsigned int), stream);
  transpose_w<<<dim3(16, 64), 256, 0, stream>>>(eWhh, WTe, 512);
  transpose_w<<<dim3(8, 64), 256, 0, stream>>>(eWih, WTe + 512 * 2048, 256);
  transpose_w<<<dim3(16, 64), 256, 0, stream>>>(dWhh, WTd, 512);
  transpose_w<<<dim3(8, 64), 256, 0, stream>>>(dWih, WTd + 512 * 2048, 256);

  {  // encoder chain
    const float* a0 = WTe; const float* a1 = x; const float* a2 = ebih;
    const float* a3 = ebhh; float* a4 = HBUF; float* a5 = Cst;
    unsigned int* a6 = CNT; int a7 = 1;
    void* args[] = {&a0, &a1, &a2, &a3, &a4, &a5, &a6, &a7};
    hipLaunchCooperativeKernel((const void*)lstm_chain, dim3(256), dim3(256), args,
                               ldsB, stream);
  }
  gemm_fp32<<<dim3(4, 128), 256, 0, stream>>>(HBUF, w1, E1, 512, 512);
  {  // decoder chain
    const float* a0 = WTd; const float* a1 = x; const float* a2 = dbih;
    const float* a3 = dbhh; float* a4 = HBUF; float* a5 = Cst;
    unsigned int* a6 = CNT + 512; int a7 = 0;
    void* args[] = {&a0, &a1, &a2, &a3, &a4, &a5, &a6, &a7};
    hipLaunchCooperativeKernel((const void*)lstm_chain, dim3(256), dim3(256), args,
                               ldsB, stream);
  }
  gemm_fp32<<<dim3(4, 128), 256, 0, stream>>>(HBUF, w2, H2, 512, 512);
  scorer<<<dim3(32, 64), 128, 0, stream>>>(E1, H2, vt, out);
  logsoftmax_kernel<<<16384, 256, 0, stream>>>(out);
}

// Round 7
// 4029.300 us; speedup vs baseline: 3.4144x; 1.1702x over previous
//
#include <hip/hip_runtime.h>
#include <cmath>

__device__ __forceinline__ float sigm(float x) { return 1.0f / (1.0f + __expf(-x)); }

// ---------------- tiled transpose [2048][K] -> [K][2048] ----------------
__global__ __launch_bounds__(256) void transpose_w(const float* __restrict__ in,
                                                   float* __restrict__ outT, int K) {
  __shared__ float tile[32][33];
  int tx = threadIdx.x & 31, ty = threadIdx.x >> 5;
  int k0 = blockIdx.x * 32;
  int j0 = blockIdx.y * 32;
#pragma unroll
  for (int i = 0; i < 32; i += 8)
    tile[ty + i][tx] = in[(size_t)(j0 + ty + i) * K + k0 + tx];
  __syncthreads();
#pragma unroll
  for (int i = 0; i < 32; i += 8)
    outT[(size_t)(k0 + ty + i) * 2048 + j0 + tx] = tile[tx][ty + i];
}

// one j-slice (32 k values / 8 per thread-kq) of the gate GEMV.
// NOTE: FMA ordering matches R5 exactly; gate accumulation order is numerics-
// critical (chaotic 256-step recurrence) — do NOT split/reorder (R6 failed).
__device__ __forceinline__ void gemv_j(const float4* __restrict__ A4,
                                       const float4* __restrict__ W4, int j, int kqx,
                                       int kq, int jlo, int jhi, int b0, int b1,
                                       float (&o0)[8], float (&o1)[8]) {
  int qa = (j << 3) + kqx;
  float4 a04 = A4[b0 * 192 + qa];
  float4 a14 = A4[b1 * 192 + qa];
  int wr = ((j << 3) + kq) << 2;  // k base (in rows of W4)
  float a0v[4] = {a04.x, a04.y, a04.z, a04.w};
  float a1v[4] = {a14.x, a14.y, a14.z, a14.w};
#pragma unroll
  for (int i = 0; i < 4; ++i) {
    float4 wlo = W4[(wr + i) * 8 + jlo];
    float4 whi = W4[(wr + i) * 8 + jhi];
    o0[0] = fmaf(a0v[i], wlo.x, o0[0]);
    o0[1] = fmaf(a0v[i], wlo.y, o0[1]);
    o0[2] = fmaf(a0v[i], wlo.z, o0[2]);
    o0[3] = fmaf(a0v[i], wlo.w, o0[3]);
    o0[4] = fmaf(a0v[i], whi.x, o0[4]);
    o0[5] = fmaf(a0v[i], whi.y, o0[5]);
    o0[6] = fmaf(a0v[i], whi.z, o0[6]);
    o0[7] = fmaf(a0v[i], whi.w, o0[7]);
    o1[0] = fmaf(a1v[i], wlo.x, o1[0]);
    o1[1] = fmaf(a1v[i], wlo.y, o1[1]);
    o1[2] = fmaf(a1v[i], wlo.z, o1[2]);
    o1[3] = fmaf(a1v[i], wlo.w, o1[3]);
    o1[4] = fmaf(a1v[i], whi.x, o1[4]);
    o1[5] = fmaf(a1v[i], whi.y, o1[5]);
    o1[6] = fmaf(a1v[i], whi.z, o1[6]);
    o1[7] = fmaf(a1v[i], whi.w, o1[7]);
  }
}

// ---- persistent fused LSTM chain: 256 steps in one cooperative launch ----
// Grid 256 = 4 bg x 64 ng. Block owns 16 batches x 8 hidden units.
// Gate GEMV: single j=0..23 chain (R5 numerics, pinned). Barrier: per-producer
// flags on separate lines (store-only release), wave 0 polls lane-parallel.
__global__ __launch_bounds__(256, 1) void lstm_chain(
    const float* __restrict__ WT, const float* __restrict__ x,
    const float* __restrict__ bih, const float* __restrict__ bhh,
    float* __restrict__ HBUF,        // [256][64][512]
    float* __restrict__ Cst,         // [64][512]
    unsigned int* __restrict__ flg,  // 4 domains x 64 flags x 32 uints
    int is_enc) {
  extern __shared__ float lds[];
  float4* W4 = (float4*)lds;            // 768 x 8 f4 (XOR-swizzled) = 96 KB
  float4* A4 = (float4*)(lds + 24576);  // 16 x 192 f4 (XOR-swizzled) = 48 KB
  float* gates = lds + 24576 + 12288;   // 16 x 40
  const int bg = blockIdx.x >> 6, ng = blockIdx.x & 63;
  const int tid = threadIdx.x;
  unsigned int* myflag = flg + (size_t)(bg * 64 + ng) * 32;
  unsigned int* dom = flg + (size_t)bg * 64 * 32;

  // ---- stage W slice once ----
#pragma unroll
  for (int r = 0; r < 24; ++r) {
    int idx = tid + 256 * r;
    int k = idx >> 3, j = idx & 7;
    float4 v =
        *(const float4*)(WT + (size_t)k * 2048 + (j >> 1) * 512 + ng * 8 + (j & 1) * 4);
    W4[k * 8 + (j ^ ((k >> 2) & 7))] = v;
  }
  // ---- per-thread cell state + biases (threads 0..127 own (b,n8)) ----
  float bi_i = 0.f, bi_f = 0.f, bi_g = 0.f, bi_o = 0.f, creg = 0.f;
  if (tid < 128) {
    int b = tid >> 3, n8 = tid & 7;
    int n_g = ng * 8 + n8;
    bi_i = bih[n_g] + bhh[n_g];
    bi_f = bih[512 + n_g] + bhh[512 + n_g];
    bi_g = bih[1024 + n_g] + bhh[1024 + n_g];
    bi_o = bih[1536 + n_g] + bhh[1536 + n_g];
    if (!is_enc) creg = Cst[(size_t)(bg * 16 + b) * 512 + n_g];
  }
  // ---- initial A-h: h0 (zeros for encoder, HBUF row 255 for decoder) ----
#pragma unroll
  for (int r = 0; r < 8; ++r) {
    int idx = tid + 256 * r;
    int b = idx >> 7, q = idx & 127;
    float4 v;
    if (is_enc)
      v = make_float4(0.f, 0.f, 0.f, 0.f);
    else
      v = *(const float4*)(HBUF + ((size_t)(255 * 64) + bg * 16 + b) * 512 + 4 * q);
    A4[b * 192 + (q ^ ((b >> 1) & 7))] = v;
  }
  // ---- initial A-x: x_0 ----
#pragma unroll
  for (int r = 0; r < 4; ++r) {
    int idx = tid + 256 * r;
    int b = idx >> 6, q = idx & 63;
    float4 v = *(const float4*)(x + ((size_t)(bg * 16 + b) * 256 + 0) * 256 + 4 * q);
    A4[b * 192 + ((128 + q) ^ ((b >> 1) & 7))] = v;
  }
  __syncthreads();

  const int w = tid >> 6;  // wave = gate (0:i 1:f 2:g 3:o)
  const int lane = tid & 63;
  const int kq = lane >> 3, b8 = lane & 7;
  const int b0 = 2 * b8, b1 = b0 + 1;
  const int jlo = (2 * w) ^ kq, jhi = (2 * w + 1) ^ kq;
  const int kqx = kq ^ b8;

  for (int t = 0; t < 256; ++t) {
    float acc0[8], acc1[8];
#pragma unroll
    for (int g = 0; g < 8; ++g) { acc0[g] = 0.f; acc1[g] = 0.f; }
#pragma unroll 2
    for (int j = 0; j < 24; ++j)  // full K=768 chain, R5 order (pinned)
      gemv_j(A4, W4, j, kqx, kq, jlo, jhi, b0, b1, acc0, acc1);
    // reduce over kq (lane-stride 8,16,32)
#pragma unroll
    for (int d = 8; d <= 32; d <<= 1) {
#pragma unroll
      for (int g = 0; g < 8; ++g) {
        acc0[g] += __shfl_xor(acc0[g], d, 64);
        acc1[g] += __shfl_xor(acc1[g], d, 64);
      }
    }
    if (kq == 0) {
#pragma unroll
      for (int g = 0; g < 8; ++g) {
        gates[b0 * 40 + w * 8 + g] = acc0[g];
        gates[b1 * 40 + w * 8 + g] = acc1[g];
      }
    }
    __syncthreads();
    // ---- cell update + h store (agent-scope write-through, no fence) ----
    if (tid < 128) {
      int b = tid >> 3, n8 = tid & 7;
      float pi = gates[b * 40 + n8] + bi_i;
      float pf = gates[b * 40 + 8 + n8] + bi_f;
      float pg = gates[b * 40 + 16 + n8] + bi_g;
      float po = gates[b * 40 + 24 + n8] + bi_o;
      float ig = sigm(pi), fg = sigm(pf), gg = tanhf(pg), og = sigm(po);
      float cn = fmaf(fg, creg, ig * gg);
      if (is_enc) creg = cn;  // decoder: cell pinned at cT
      float hn = og * tanhf(cn);
      float* hp = HBUF + ((size_t)t * 64 + bg * 16 + b) * 512 + ng * 8 + n8;
      __hip_atomic_store(hp, hn, __ATOMIC_RELAXED, __HIP_MEMORY_SCOPE_AGENT);
      if (is_enc && t == 255) Cst[(size_t)(bg * 16 + b) * 512 + ng * 8 + n8] = cn;
    }
    if (t == 255) break;
    // all h of this block at the coherent point before the flag store
    asm volatile("s_waitcnt vmcnt(0)" ::: "memory");
    __syncthreads();
    if (tid == 0)
      __hip_atomic_store(myflag, (unsigned)(t + 1), __ATOMIC_RELAXED,
                         __HIP_MEMORY_SCOPE_AGENT);
    asm volatile("" ::: "memory");  // keep the flag store ahead of the staging
    // ---- stage x_{t+1} (cached, flag-independent) — shadows flag latency ----
#pragma unroll
    for (int r = 0; r < 4; ++r) {
      int idx = tid + 256 * r;
      int b = idx >> 6, q = idx & 63;
      float4 v =
          *(const float4*)(x + ((size_t)(bg * 16 + b) * 256 + (t + 1)) * 256 + 4 * q);
      A4[b * 192 + ((128 + q) ^ ((b >> 1) & 7))] = v;
    }
    // ---- wave 0: poll all 64 producer flags lane-parallel ----
    if (tid < 64) {
      const unsigned tgt = (unsigned)(t + 1);
      unsigned int* fp = dom + (size_t)tid * 32;
      while (true) {
        unsigned v = __hip_atomic_load(fp, __ATOMIC_RELAXED, __HIP_MEMORY_SCOPE_AGENT);
        if (__all((int)(v >= tgt))) break;
        __builtin_amdgcn_s_sleep(1);
      }
    }
    __syncthreads();
    // ---- h restage: plain vectorized loads (first touch after data landed) ----
    const float4* hb = (const float4*)(HBUF + (size_t)t * 64 * 512);
#pragma unroll
    for (int r = 0; r < 8; ++r) {
      int idx = tid + 256 * r;
      int b = idx >> 7, q = idx & 127;
      float4 v = hb[(size_t)(bg * 16 + b) * 128 + q];
      A4[b * 192 + (q ^ ((b >> 1) & 7))] = v;
    }
    __syncthreads();
  }
}

// ---- GEMM: C[r,n] = sum_k A[r][k] * W[n,k] ; 128x128 tile, 8x8 micro ----
__global__ __launch_bounds__(256) void gemm_fp32(const float* __restrict__ A,
                                                 const float* __restrict__ W,
                                                 float* __restrict__ C, int N, int K) {
  __shared__ float As[16 * 132];
  __shared__ float Ws[16 * 132];
  int tid = threadIdx.x;
  int n0 = blockIdx.x * 128, m0 = blockIdx.y * 128;
  int row = tid >> 1;
  int kbase = (tid & 1) * 8;
  const float* ap = A + (size_t)(m0 + row) * K;
  const float* wp = W + (size_t)(n0 + row) * K;
  int ty = tid >> 4, tx = tid & 15;
  float acc[8][8];
#pragma unroll
  for (int i = 0; i < 8; ++i)
#pragma unroll
    for (int j = 0; j < 8; ++j) acc[i][j] = 0.f;

  for (int kt = 0; kt < K; kt += 16) {
    float4 va0 = *(const float4*)(ap + kt + kbase);
    float4 va1 = *(const float4*)(ap + kt + kbase + 4);
    float4 vw0 = *(const float4*)(wp + kt + kbase);
    float4 vw1 = *(const float4*)(wp + kt + kbase + 4);
    __syncthreads();
    As[(kbase + 0) * 132 + row] = va0.x;
    As[(kbase + 1) * 132 + row] = va0.y;
    As[(kbase + 2) * 132 + row] = va0.z;
    As[(kbase + 3) * 132 + row] = va0.w;
    As[(kbase + 4) * 132 + row] = va1.x;
    As[(kbase + 5) * 132 + row] = va1.y;
    As[(kbase + 6) * 132 + row] = va1.z;
    As[(kbase + 7) * 132 + row] = va1.w;
    Ws[(kbase + 0) * 132 + row] = vw0.x;
    Ws[(kbase + 1) * 132 + row] = vw0.y;
    Ws[(kbase + 2) * 132 + row] = vw0.z;
    Ws[(kbase + 3) * 132 + row] = vw0.w;
    Ws[(kbase + 4) * 132 + row] = vw1.x;
    Ws[(kbase + 5) * 132 + row] = vw1.y;
    Ws[(kbase + 6) * 132 + row] = vw1.z;
    Ws[(kbase + 7) * 132 + row] = vw1.w;
    __syncthreads();
#pragma unroll
    for (int kk = 0; kk < 16; ++kk) {
      float4 a0 = *(const float4*)&As[kk * 132 + ty * 8];
      float4 a1 = *(const float4*)&As[kk * 132 + ty * 8 + 4];
      float4 w0 = *(const float4*)&Ws[kk * 132 + tx * 8];
      float4 w1 = *(const float4*)&Ws[kk * 132 + tx * 8 + 4];
      float av[8] = {a0.x, a0.y, a0.z, a0.w, a1.x, a1.y, a1.z, a1.w};
      float wv[8] = {w0.x, w0.y, w0.z, w0.w, w1.x, w1.y, w1.z, w1.w};
#pragma unroll
      for (int i = 0; i < 8; ++i)
#pragma unroll
        for (int j = 0; j < 8; ++j) acc[i][j] = fmaf(av[i], wv[j], acc[i][j]);
    }
  }
#pragma unroll
  for (int i = 0; i < 8; ++i) {
    float* cp = C + (size_t)(m0 + ty * 8 + i) * N + n0 + tx * 8;
    *(float4*)cp = make_float4(acc[i][0], acc[i][1], acc[i][2], acc[i][3]);
    *(float4*)(cp + 4) = make_float4(acc[i][4], acc[i][5], acc[i][6], acc[i][7]);
  }
}

// ---- scorer: out[b,t,s] = sum_w vt[w]*tanh(e1[s,b,w] + H2[t,b,w]) ----
// 256 threads, 16x16 (t,s) tile, dynamic LDS 66 KB -> 2 blocks/CU, 8 waves/CU.
__global__ __launch_bounds__(256) void scorer(const float* __restrict__ E1,
                                              const float* __restrict__ H2,
                                              const float* __restrict__ vt,
                                              float* __restrict__ out) {
  extern __shared__ float smem[];
  float* e1s = smem;         // 16 x 516
  float* h2s = smem + 8256;  // 16 x 516
  int tid = threadIdx.x;
  int sx = blockIdx.x;  // 16 s-tiles of 16
  int b = blockIdx.y;
#pragma unroll
  for (int j = 0; j < 8; ++j) {
    int idx = tid + 256 * j;
    int r = idx >> 7, c4 = idx & 127;
    float4 v = *(const float4*)(E1 + ((size_t)(sx * 16 + r) * 64 + b) * 512 + c4 * 4);
    *(float4*)&e1s[r * 516 + c4 * 4] = v;
  }
  int tl = tid >> 4, sl = tid & 15;
  for (int tt = 0; tt < 16; ++tt) {
    __syncthreads();
#pragma unroll
    for (int j = 0; j < 8; ++j) {
      int idx = tid + 256 * j;
      int r = idx >> 7, c4 = idx & 127;
      float4 v = *(const float4*)(H2 + ((size_t)(tt * 16 + r) * 64 + b) * 512 + c4 * 4);
      *(float4*)&h2s[r * 516 + c4 * 4] = v;
    }
    __syncthreads();
    float acc = 0.f;
    const float* ep = &e1s[sl * 516];
    const float* hp = &h2s[tl * 516];
#pragma unroll 8
    for (int w4 = 0; w4 < 128; ++w4) {
      float4 a = *(const float4*)(ep + w4 * 4);
      float4 h = *(const float4*)(hp + w4 * 4);
      float4 vv = *(const float4*)(vt + w4 * 4);
      float x0 = a.x + h.x, x1 = a.y + h.y, x2 = a.z + h.z, x3 = a.w + h.w;
      float t0 = fmaf(-2.f, __builtin_amdgcn_rcpf(__expf(x0 + x0) + 1.f), 1.f);
      float t1 = fmaf(-2.f, __builtin_amdgcn_rcpf(__expf(x1 + x1) + 1.f), 1.f);
      float t2 = fmaf(-2.f, __builtin_amdgcn_rcpf(__expf(x2 + x2) + 1.f), 1.f);
      float t3 = fmaf(-2.f, __builtin_amdgcn_rcpf(__expf(x3 + x3) + 1.f), 1.f);
      acc = fmaf(t0, vv.x, acc);
      acc = fmaf(t1, vv.y, acc);
      acc = fmaf(t2, vv.z, acc);
      acc = fmaf(t3, vv.w, acc);
    }
    out[((size_t)b * 256 + tt * 16 + tl) * 256 + sx * 16 + sl] = acc;
  }
}

// ---- in-place log_softmax over rows of 256 ----
__global__ __launch_bounds__(256) void logsoftmax_kernel(float* __restrict__ out) {
  __shared__ float red[256];
  int tid = threadIdx.x;
  float* row = out + (size_t)blockIdx.x * 256;
  float v = row[tid];
  red[tid] = v;
  __syncthreads();
  for (int off = 128; off > 0; off >>= 1) {
    if (tid < off) red[tid] = fmaxf(red[tid], red[tid + off]);
    __syncthreads();
  }
  float mx = red[0];
  __syncthreads();
  red[tid] = __expf(v - mx);
  __syncthreads();
  for (int off = 128; off > 0; off >>= 1) {
    if (tid < off) red[tid] += red[tid + off];
    __syncthreads();
  }
  float lse = logf(red[0]);
  row[tid] = v - mx - lse;
}

extern "C" void kernel_launch(void* const* d_in, const int* in_sizes, int n_in,
                              void* d_out, int out_size, void* d_ws, size_t ws_size,
                              hipStream_t stream) {
  (void)in_sizes; (void)n_in; (void)out_size; (void)ws_size;
  const float* x = (const float*)d_in[0];
  const float* eWih = (const float*)d_in[1];
  const float* eWhh = (const float*)d_in[2];
  const float* ebih = (const float*)d_in[3];
  const float* ebhh = (const float*)d_in[4];
  const float* dWih = (const float*)d_in[5];
  const float* dWhh = (const float*)d_in[6];
  const float* dbih = (const float*)d_in[7];
  const float* dbhh = (const float*)d_in[8];
  const float* w1 = (const float*)d_in[9];
  const float* w2 = (const float*)d_in[10];
  const float* vt = (const float*)d_in[11];
  float* out = (float*)d_out;
  float* ws = (float*)d_ws;

  // workspace (floats) — ~113.5 MB
  float* E1 = ws;                  //  8,388,608  [S,B,W]
  float* H2 = E1 + 8388608ull;     //  8,388,608  [S,B,W]
  float* HBUF = H2 + 8388608ull;   //  8,388,608  [S,B,H] enc then dec h
  float* WTe = HBUF + 8388608ull;  //  1,572,864  [768][2048]
  float* WTd = WTe + 1572864ull;   //  1,572,864
  float* Cst = WTd + 1572864ull;   //     32,768
  unsigned int* FLG = (unsigned int*)(Cst + 32768ull);  // 2 x 8192 uints (64 KB)

  const unsigned ldsB = (24576 + 12288 + 640) * 4;  // 150,016 B
  const unsigned scorerLds = 2 * 16 * 516 * 4;      // 66,048 B

  hipMemsetAsync(FLG, 0, 16384 * sizeof(unsigned int), stream);
  transpose_w<<<dim3(16, 64), 256, 0, stream>>>(eWhh, WTe, 512);
  transpose_w<<<dim3(8, 64), 256, 0, stream>>>(eWih, WTe + 512 * 2048, 256);
  transpose_w<<<dim3(16, 64), 256, 0, stream>>>(dWhh, WTd, 512);
  transpose_w<<<dim3(8, 64), 256, 0, stream>>>(dWih, WTd + 512 * 2048, 256);

  {  // encoder chain
    const float* a0 = WTe; const float* a1 = x; const float* a2 = ebih;
    const float* a3 = ebhh; float* a4 = HBUF; float* a5 = Cst;
    unsigned int* a6 = FLG; int a7 = 1;
    void* args[] = {&a0, &a1, &a2, &a3, &a4, &a5, &a6, &a7};
    hipLaunchCooperativeKernel((const void*)lstm_chain, dim3(256), dim3(256), args,
                               ldsB, stream);
  }
  gemm_fp32<<<dim3(4, 128), 256, 0, stream>>>(HBUF, w1, E1, 512, 512);
  {  // decoder chain
    const float* a0 = WTd; const float* a1 = x; const float* a2 = dbih;
    const float* a3 = dbhh; float* a4 = HBUF; float* a5 = Cst;
    unsigned int* a6 = FLG + 8192; int a7 = 0;
    void* args[] = {&a0, &a1, &a2, &a3, &a4, &a5, &a6, &a7};
    hipLaunchCooperativeKernel((const void*)lstm_chain, dim3(256), dim3(256), args,
                               ldsB, stream);
  }
  gemm_fp32<<<dim3(4, 128), 256, 0, stream>>>(HBUF, w2, H2, 512, 512);
  scorer<<<dim3(16, 64), 256, scorerLds, stream>>>(E1, H2, vt, out);
  logsoftmax_kernel<<<16384, 256, 0, stream>>>(out);
}